// Round 2
// baseline (492.545 us; speedup 1.0000x reference)
//
#include <hip/hip_runtime.h>

typedef __bf16 bf16_t;
typedef __bf16 bf16x8 __attribute__((ext_vector_type(8)));
typedef __bf16 bf16x4 __attribute__((ext_vector_type(4)));
typedef float  f32x4  __attribute__((ext_vector_type(4)));

#define HW_ 65536
#define C_  128

// XOR swizzle: spread 16B slots (byte bits [6:4]) by row index. Applied
// identically on LDS write and read; bijective within each 128B span.
__device__ __forceinline__ int swz(int r) { return ((r ^ (r >> 3)) & 7) << 4; }

// =====================================================================
// Phase 1: map = PReLU(W*x + b) for f,g,h.  Per-b GEMM M=128,K=128,N=128/WG.
// (unchanged from R1 — ~154us, attn was the bottleneck)
// =====================================================================
template<bool HBLK>
__device__ __forceinline__ void conv_one(char* lds, const float* __restrict__ Wsrc,
                                         const float* __restrict__ bias, float alpha,
                                         bf16_t* __restrict__ dst, size_t pb,
                                         int wv, int lr, int lq, int t, int s0)
{
  __syncthreads();
  #pragma unroll
  for (int rep = 0; rep < 16; ++rep) {
    int q = rep * 256 + t;
    int o = q >> 5, c0 = (q & 31) * 4;
    f32x4 w4 = *(const f32x4*)(Wsrc + o * C_ + c0);
    bf16x4 v;
    v[0] = (bf16_t)w4[0]; v[1] = (bf16_t)w4[1]; v[2] = (bf16_t)w4[2]; v[3] = (bf16_t)w4[3];
    *(bf16x4*)(lds + 32768 + ((o * 256 + c0 * 2) ^ swz(o))) = v;
  }
  __syncthreads();

  const f32x4 fz = {0.f, 0.f, 0.f, 0.f};
  f32x4 acc[2][8];
  #pragma unroll
  for (int mf = 0; mf < 2; ++mf)
    #pragma unroll
    for (int nf = 0; nf < 8; ++nf)
      acc[mf][nf] = fz;

  #pragma unroll
  for (int ks = 0; ks < 4; ++ks) {
    int kb = ks * 32 + lq * 8;
    bf16x8 a[2], bb[8];
    #pragma unroll
    for (int mf = 0; mf < 2; ++mf) {
      int m = wv * 32 + mf * 16 + lr;
      a[mf] = *(const bf16x8*)(lds + 32768 + ((m * 256 + kb * 2) ^ swz(m)));
    }
    #pragma unroll
    for (int nf = 0; nf < 8; ++nf) {
      int n = nf * 16 + lr;
      bb[nf] = *(const bf16x8*)(lds + ((n * 256 + kb * 2) ^ swz(n)));
    }
    #pragma unroll
    for (int mf = 0; mf < 2; ++mf)
      #pragma unroll
      for (int nf = 0; nf < 8; ++nf)
        acc[mf][nf] = __builtin_amdgcn_mfma_f32_16x16x32_bf16(a[mf], bb[nf], acc[mf][nf], 0, 0, 0);
  }

  #pragma unroll
  for (int mf = 0; mf < 2; ++mf) {
    #pragma unroll
    for (int i = 0; i < 4; ++i) {
      int o = wv * 32 + mf * 16 + lq * 4 + i;
      float bo = bias[o];
      #pragma unroll
      for (int nf = 0; nf < 8; ++nf) {
        int s = s0 + nf * 16 + lr;
        float v = acc[mf][nf][i] + bo;
        v = (v >= 0.f) ? v : alpha * v;
        size_t off;
        if (HBLK) {                       // w-blocked layout [c][w>>6][h][w&63]
          int h = s >> 8, w = s & 255;
          off = pb + (size_t)o * HW_ + (size_t)(w >> 6) * 16384 + h * 64 + (w & 63);
        } else {
          off = pb + (size_t)o * HW_ + s; // natural [c][h][w]
        }
        dst[off] = (bf16_t)v;
      }
    }
  }
}

__global__ __launch_bounds__(256, 2) void conv_kernel(
    const float* __restrict__ x,
    const float* __restrict__ Wf, const float* __restrict__ bfp, const float* __restrict__ afp,
    const float* __restrict__ Wg, const float* __restrict__ bgp, const float* __restrict__ agp,
    const float* __restrict__ Wh, const float* __restrict__ bhp, const float* __restrict__ ahp,
    bf16_t* __restrict__ mF, bf16_t* __restrict__ mG, bf16_t* __restrict__ mH, int b0)
{
  __shared__ __align__(16) char lds[65536];
  const int t = threadIdx.x;
  const int bloc = blockIdx.y;
  const int s0 = blockIdx.x * 128;
  const size_t xbase = ((size_t)(b0 + bloc) * C_) * HW_ + s0;

  #pragma unroll
  for (int rep = 0; rep < 4; ++rep) {
    int q = rep * 256 + t;
    int c0 = (q >> 5) * 4, sl0 = (q & 31) * 4;
    f32x4 r[4];
    #pragma unroll
    for (int i = 0; i < 4; ++i)
      r[i] = *(const f32x4*)(x + xbase + (size_t)(c0 + i) * HW_ + sl0);
    #pragma unroll
    for (int js = 0; js < 4; ++js) {
      int s = sl0 + js;
      bf16x4 v;
      v[0] = (bf16_t)r[0][js]; v[1] = (bf16_t)r[1][js];
      v[2] = (bf16_t)r[2][js]; v[3] = (bf16_t)r[3][js];
      *(bf16x4*)(lds + ((s * 256 + c0 * 2) ^ swz(s))) = v;
    }
  }

  const int wv = t >> 6, lane = t & 63, lr = lane & 15, lq = lane >> 4;
  const size_t pb = (size_t)bloc * C_ * HW_;
  conv_one<false>(lds, Wf, bfp, afp[0], mF, pb, wv, lr, lq, t, s0);
  conv_one<false>(lds, Wg, bgp, agp[0], mG, pb, wv, lr, lq, t, s0);
  conv_one<true >(lds, Wh, bhp, ahp[0], mH, pb, wv, lr, lq, t, s0);
}

// =====================================================================
// Phase 2 (REWRITTEN): 1024 threads = 16 waves (wr 0..3 x wc 0..3), 1 WG/CU,
// 4 waves/SIMD.  Per (b,c): S = F^T G (64 f32 acc/lane), softmax over v,
// P -> bf16 -> full PT[v=256][w=256] LDS (128KB), then out = H*P with H
// A-fragments loaded DIRECTLY from global (w-blocked mH, 64B-coalesced,
// each element read once) -> zero barriers in the PV main loop.
// LDS map (139264 B):
//   [0,32768)        Ft chunk [w=256][h=64] bf16 swizzled   (S phase)
//   [32768,65536)    Gt chunk [v=256][h=64] bf16 swizzled   (S phase)
//   [0,131072)       PT       [v=256][w=256] bf16 swizzled  (PV phase)
//   [131072,135168)  smax[4][256] f32 ;  [135168,139264) ssum[4][256] f32
// =====================================================================
#define SMAX_OFF 131072
#define SSUM_OFF 135168
#define ATTN_SMEM 139264

__global__ __launch_bounds__(1024, 4) void attn_kernel(
    const bf16_t* __restrict__ mF, const bf16_t* __restrict__ mG, const bf16_t* __restrict__ mH,
    const float* __restrict__ x, float* __restrict__ out, int b0)
{
  extern __shared__ __align__(16) char smem[];
  const int t = threadIdx.x;
  const int c = blockIdx.x, bloc = blockIdx.y;
  const int lane = t & 63, lr = lane & 15, lq = lane >> 4;
  const int wv = t >> 6, wr = wv >> 2, wc = wv & 3;
  const size_t plane  = ((size_t)bloc * C_ + c) * HW_;            // maps (per-pass)
  const size_t gplane = (((size_t)(b0 + bloc)) * C_ + c) * HW_;   // x / out (global)

  const f32x4 fz = {0.f, 0.f, 0.f, 0.f};
  f32x4 acc[4][4];
  #pragma unroll
  for (int mf = 0; mf < 4; ++mf)
    #pragma unroll
    for (int nf = 0; nf < 4; ++nf)
      acc[mf][nf] = fz;

  // ---- S = F^T G, K(=h) chunks of 64, register-transpose staging + prefetch ----
  const int sg = t >> 9;              // waves 0..7 stage F, 8..15 stage G
  const int u  = t & 511;
  const int w0 = (u & 31) * 8, h0 = (u >> 5) * 4;
  const bf16_t* sp = sg ? mG : mF;
  char* sd = smem + sg * 32768;

  bf16x8 pf[4];
  #pragma unroll
  for (int i = 0; i < 4; ++i)
    pf[i] = *(const bf16x8*)(sp + plane + (size_t)(h0 + i) * 256 + w0);

  #pragma unroll
  for (int hc = 0; hc < 4; ++hc) {
    #pragma unroll
    for (int j = 0; j < 8; ++j) {
      int w = w0 + j;
      bf16x4 v; v[0] = pf[0][j]; v[1] = pf[1][j]; v[2] = pf[2][j]; v[3] = pf[3][j];
      *(bf16x4*)(sd + ((w * 128 + h0 * 2) ^ swz(w))) = v;
    }
    if (hc < 3) {                     // prefetch next chunk (latency hidden under MFMA)
      #pragma unroll
      for (int i = 0; i < 4; ++i)
        pf[i] = *(const bf16x8*)(sp + plane + (size_t)((hc + 1) * 64 + h0 + i) * 256 + w0);
    }
    __syncthreads();
    #pragma unroll
    for (int k0 = 0; k0 < 64; k0 += 32) {
      const int kb = k0 + lq * 8;
      bf16x8 af[4], bq[4];
      #pragma unroll
      for (int mf = 0; mf < 4; ++mf) {
        int m = wr * 64 + mf * 16 + lr;
        af[mf] = *(const bf16x8*)(smem + ((m * 128 + kb * 2) ^ swz(m)));
      }
      #pragma unroll
      for (int nf = 0; nf < 4; ++nf) {
        int n = wc * 64 + nf * 16 + lr;
        bq[nf] = *(const bf16x8*)(smem + 32768 + ((n * 128 + kb * 2) ^ swz(n)));
      }
      #pragma unroll
      for (int mf = 0; mf < 4; ++mf)
        #pragma unroll
        for (int nf = 0; nf < 4; ++nf)
          acc[mf][nf] = __builtin_amdgcn_mfma_f32_16x16x32_bf16(af[mf], bq[nf], acc[mf][nf], 0, 0, 0);
    }
    __syncthreads();
  }

  // ---- softmax over v (rows w), cross-wave combine over 4 wc groups ----
  float* smax = (float*)(smem + SMAX_OFF);
  float* ssum = (float*)(smem + SSUM_OFF);
  float rinv[4][4];
  {
    float rowm[4][4];
    #pragma unroll
    for (int mf = 0; mf < 4; ++mf)
      #pragma unroll
      for (int i = 0; i < 4; ++i) {
        float m = fmaxf(fmaxf(acc[mf][0][i], acc[mf][1][i]),
                        fmaxf(acc[mf][2][i], acc[mf][3][i]));
        #pragma unroll
        for (int d = 1; d < 16; d <<= 1) m = fmaxf(m, __shfl_xor(m, d));
        rowm[mf][i] = m;
      }
    if (lr == 0) {
      #pragma unroll
      for (int mf = 0; mf < 4; ++mf)
        #pragma unroll
        for (int i = 0; i < 4; ++i)
          smax[wc * 256 + wr * 64 + mf * 16 + lq * 4 + i] = rowm[mf][i];
    }
    __syncthreads();
    #pragma unroll
    for (int mf = 0; mf < 4; ++mf)
      #pragma unroll
      for (int i = 0; i < 4; ++i) {
        int w = wr * 64 + mf * 16 + lq * 4 + i;
        rowm[mf][i] = fmaxf(fmaxf(smax[w], smax[256 + w]),
                            fmaxf(smax[512 + w], smax[768 + w]));
      }
    #pragma unroll
    for (int mf = 0; mf < 4; ++mf)
      #pragma unroll
      for (int i = 0; i < 4; ++i) {
        float rs = 0.f;
        #pragma unroll
        for (int nf = 0; nf < 4; ++nf) {
          float e = __expf(acc[mf][nf][i] - rowm[mf][i]);
          acc[mf][nf][i] = e;
          rs += e;
        }
        #pragma unroll
        for (int d = 1; d < 16; d <<= 1) rs += __shfl_xor(rs, d);
        if (lr == 0) ssum[wc * 256 + wr * 64 + mf * 16 + lq * 4 + i] = rs;
      }
    __syncthreads();
    #pragma unroll
    for (int mf = 0; mf < 4; ++mf)
      #pragma unroll
      for (int i = 0; i < 4; ++i) {
        int w = wr * 64 + mf * 16 + lq * 4 + i;
        rinv[mf][i] = 1.f / (ssum[w] + ssum[256 + w] + ssum[512 + w] + ssum[768 + w]);
      }
  }

  // ---- prefetch H for ks=0 (hidden under P-write + barrier) ----
  bf16x8 aA[4], aB[4];
  #pragma unroll
  for (int mf = 0; mf < 4; ++mf) {
    int h = wr * 64 + mf * 16 + lr;
    aA[mf] = *(const bf16x8*)(mH + plane + (size_t)h * 64 + lq * 8);
  }

  // ---- P = e * rinv -> bf16 -> PT[v][w] (i-packed 8B writes) ----
  #pragma unroll
  for (int mf = 0; mf < 4; ++mf) {
    int wpb = (wr * 64 + mf * 16 + lq * 4) * 2;
    #pragma unroll
    for (int nf = 0; nf < 4; ++nf) {
      int v_ = wc * 64 + nf * 16 + lr;
      bf16x4 v;
      #pragma unroll
      for (int i = 0; i < 4; ++i) v[i] = (bf16_t)(acc[mf][nf][i] * rinv[mf][i]);
      *(bf16x4*)(smem + ((v_ * 512 + wpb) ^ swz(v_))) = v;
    }
  }
  // prefetch H for ks=1
  #pragma unroll
  for (int mf = 0; mf < 4; ++mf) {
    int h = wr * 64 + mf * 16 + lr;
    aB[mf] = *(const bf16x8*)(mH + plane + (size_t)h * 64 + 32 + lq * 8);
  }

  #pragma unroll
  for (int mf = 0; mf < 4; ++mf)
    #pragma unroll
    for (int nf = 0; nf < 4; ++nf)
      acc[mf][nf] = fz;
  __syncthreads();

  // ---- out = H*P: 8 K-steps, A direct-from-global 2-deep pipeline, no barriers ----
#define PV_STEP(KS, AC)                                                          \
  {                                                                              \
    bf16x8 bq[4];                                                                \
    _Pragma("unroll")                                                            \
    for (int nf = 0; nf < 4; ++nf) {                                             \
      int v_ = wc * 64 + nf * 16 + lr;                                           \
      bq[nf] = *(const bf16x8*)(smem + ((v_ * 512 + (KS) * 64 + lq * 16) ^ swz(v_))); \
    }                                                                            \
    _Pragma("unroll")                                                            \
    for (int mf = 0; mf < 4; ++mf)                                               \
      _Pragma("unroll")                                                          \
      for (int nf = 0; nf < 4; ++nf)                                             \
        acc[mf][nf] = __builtin_amdgcn_mfma_f32_16x16x32_bf16(AC[mf], bq[nf], acc[mf][nf], 0, 0, 0); \
    if ((KS) < 6) {                                                              \
      _Pragma("unroll")                                                          \
      for (int mf = 0; mf < 4; ++mf) {                                           \
        int h = wr * 64 + mf * 16 + lr;                                          \
        AC[mf] = *(const bf16x8*)(mH + plane + (size_t)(((KS) + 2) >> 1) * 16384 \
                                  + (size_t)h * 64 + (((KS) + 2) & 1) * 32 + lq * 8); \
      }                                                                          \
    }                                                                            \
  }

  PV_STEP(0, aA) PV_STEP(1, aB) PV_STEP(2, aA) PV_STEP(3, aB)
  PV_STEP(4, aA) PV_STEP(5, aB) PV_STEP(6, aA) PV_STEP(7, aB)
#undef PV_STEP

  // ---- residual + store f32 ----
  #pragma unroll
  for (int mf = 0; mf < 4; ++mf)
    #pragma unroll
    for (int i = 0; i < 4; ++i) {
      int h = wr * 64 + mf * 16 + lq * 4 + i;
      #pragma unroll
      for (int nf = 0; nf < 4; ++nf) {
        int v_ = wc * 64 + nf * 16 + lr;
        size_t off = gplane + (size_t)h * 256 + v_;
        out[off] = acc[mf][nf][i] + x[off];
      }
    }
}

// =====================================================================
extern "C" void kernel_launch(void* const* d_in, const int* in_sizes, int n_in,
                              void* d_out, int out_size, void* d_ws, size_t ws_size,
                              hipStream_t stream)
{
  (void)in_sizes; (void)n_in; (void)out_size;
  const float* x   = (const float*)d_in[0];
  const float* Wf  = (const float*)d_in[1];
  const float* bfp = (const float*)d_in[2];
  const float* afp = (const float*)d_in[3];
  const float* Wg  = (const float*)d_in[4];
  const float* bgp = (const float*)d_in[5];
  const float* agp = (const float*)d_in[6];
  const float* Wh  = (const float*)d_in[7];
  const float* bhp = (const float*)d_in[8];
  const float* ahp = (const float*)d_in[9];
  float* out = (float*)d_out;

  const size_t per_map_b = (size_t)C_ * HW_ * sizeof(bf16_t);  // 16 MiB per map per batch
  int nb = 1;
  if      (ws_size >= 3 * 8 * per_map_b) nb = 8;
  else if (ws_size >= 3 * 4 * per_map_b) nb = 4;
  else if (ws_size >= 3 * 2 * per_map_b) nb = 2;

  hipFuncSetAttribute(reinterpret_cast<const void*>(attn_kernel),
                      hipFuncAttributeMaxDynamicSharedMemorySize, ATTN_SMEM);

  bf16_t* mF = (bf16_t*)d_ws;
  bf16_t* mG = mF + (size_t)nb * C_ * HW_;
  bf16_t* mH = mG + (size_t)nb * C_ * HW_;

  for (int b0 = 0; b0 < 8; b0 += nb) {
    conv_kernel<<<dim3(512, nb), 256, 0, stream>>>(x, Wf, bfp, afp, Wg, bgp, agp,
                                                   Wh, bhp, ahp, mF, mG, mH, b0);
    attn_kernel<<<dim3(C_, nb), 1024, ATTN_SMEM, stream>>>(mF, mG, mH, x, out, b0);
  }
}